// Round 15
// baseline (545.724 us; speedup 1.0000x reference)
//
#include <hip/hip_runtime.h>
#include <cstdint>
#include <cstddef>

// ---------------------------------------------------------------------------
// CapsNet forward. Round 20: R19 (measured 473us, = best 470) + conv1
// reg-window rewrite RETRY with the R18 spill fixed.
//  R18 diagnosis: compiler capped k_pre at 68 VGPR (default occupancy
//  heuristic) while the reg-window conv1 needs ~106 live -> spill to
//  scratch (WRITE_SIZE 52->120MB, VALUBusy 59%, 149us). R18 PASSED
//  correctness, so the numerics are proven. Fix: __launch_bounds__(256,1)
//  (min 1 wave/EU -> VGPR budget up to 512). At ~128 VGPR: 4 waves/SIMD,
//  13.5KB LDS -> 4 blocks/CU, VALU-bound ~40us (vs ~70us LDS version:
//  ~2400 ds_read/thread).
//  Failed-path ledger (all measured): conv2m pipelined variants 150-153 vs
//  142 (R6 schedule kept); softmax-into-gemm1 +27us; cooperative grid.sync
//  wrong under capture; hand-rolled barrier ~36us/barrier constant (per-XCD
//  L2 wb/inv) -> relaunch cheaper; plain-load barrier poll hangs.
// Workspace (bytes):
//   h    [0, 52428800)           bf16 [b][pix400][ic256]   (dead after conv2m)
//   dwT2 [0, 5898240)            f32  [co160][ik9216]      (aliases h)
//   wt   [52428800, 63045632)    bf16 [k81][oc256][ic256]
//   pp0  [63045632, 72482816)    f32  partial (half0,seg0) [b][oc][36]
//   pp1  [72482816, 81920000)    f32  partial (half0,seg1)
//   U    [81920000, 91357184)    f32  [b][ik]
//   pp3  [91357184, 100794368)   f32  partial (half1,seg1)
//   part [97255424, 102498304)   f32  [kc32][b256][co160]
//   csm  [102498304,102544384)   f32  [i][c]
//   bij  [102544384,102590464)   f32  [i][c]
//   outT [102590464,102754304)   f32  [co160][b256]
//   outw [102754304,102918144)   f32  [b][co160]
//   pp2  [102918144,112355328)   f32  partial (half1,seg0)
// ---------------------------------------------------------------------------

typedef __attribute__((ext_vector_type(8))) short short8;
typedef __attribute__((ext_vector_type(4))) float f32x4;

#define PHALF 2359296

__device__ __forceinline__ unsigned short f2bf_rn(float x) {
    unsigned u = __float_as_uint(x);
    unsigned r = (u + 0x7fffu + ((u >> 16) & 1u)) >> 16;
    return (unsigned short)r;
}

// Fused preprocessing: blocks 0..2047 conv1, blocks 2048..4095 makew.
// conv1: thread = 2 px; 9x10 window in regs; wave-uniform weight s_loads;
// oc8-packed uint4 stores. __launch_bounds__(256,1) -> no VGPR spill.
__global__ __launch_bounds__(256, 1) void k_pre(
    const float* __restrict__ x, const float* __restrict__ cw,
    const float* __restrict__ cb, const float* __restrict__ w2,
    unsigned short* __restrict__ h, unsigned short* __restrict__ wt) {
    __shared__ float sh[2592];
    int blk = blockIdx.x, t = threadIdx.x;
    if (blk < 2048) {
        float* img = sh;            // 784 used
        int b = blk >> 3, ocg = blk & 7;
        for (int idx = t; idx < 784; idx += 256) img[idx] = x[b * 784 + idx];
        __syncthreads();
        if (t < 200) {
            int py = t / 10, qx = (t % 10) * 2;
            float win[9][10];
            #pragma unroll
            for (int ky = 0; ky < 9; ky++)
                #pragma unroll
                for (int c = 0; c < 10; c++)
                    win[ky][c] = img[(py + ky) * 28 + qx + c];
            size_t base0 = ((size_t)b * 400 + py * 20 + qx) * 256 + ocg * 32;
            size_t base1 = base0 + 256;
            for (int oc8 = 0; oc8 < 4; ++oc8) {
                unsigned short hb0[8], hb1[8];
                #pragma unroll
                for (int j = 0; j < 8; j++) {
                    int oc = ocg * 32 + oc8 * 8 + j;           // wave-uniform
                    const float* wp = cw + oc * 81;            // -> s_load
                    float a0 = cb[oc], a1 = a0;
                    #pragma unroll
                    for (int ky = 0; ky < 9; ky++)
                        #pragma unroll
                        for (int kx = 0; kx < 9; kx++) {
                            float w = wp[ky * 9 + kx];
                            a0 += win[ky][kx] * w;
                            a1 += win[ky][kx + 1] * w;
                        }
                    hb0[j] = f2bf_rn(fmaxf(a0, 0.f));
                    hb1[j] = f2bf_rn(fmaxf(a1, 0.f));
                }
                *(uint4*)&h[base0 + oc8 * 8] = *(uint4*)hb0;
                *(uint4*)&h[base1 + oc8 * 8] = *(uint4*)hb1;
            }
        }
    } else {
        int m2 = blk - 2048;
        int oc = m2 >> 3, icg = m2 & 7;
        float* lw2 = sh;            // 2592 = [32 ic][81 k]
        for (int idx = t; idx < 2592; idx += 256) {
            int ic_l = idx / 81, k = idx % 81;
            lw2[idx] = w2[((size_t)oc * 256 + icg * 32 + ic_l) * 81 + k];
        }
        __syncthreads();
        for (int idx = t; idx < 324; idx += 256) {   // 81 k * 4 slots
            int k = idx >> 2, sl = idx & 3;
            unsigned short hi8[8];
            #pragma unroll
            for (int j = 0; j < 8; j++)
                hi8[j] = f2bf_rn(lw2[(sl * 8 + j) * 81 + k]);
            size_t o = ((size_t)(k * 256 + oc)) * 256 + icg * 32 + sl * 8;
            *(uint4*)&wt[o] = *(uint4*)hi8;
        }
    }
}

// Implicit-GEMM bf16 MFMA conv2 — ROUND-6 schedule (best measured).
// grid (96 mb, 2 nb, 4 zz) = 768 blocks (3/CU), block 256 (4 waves).
__global__ __launch_bounds__(256, 4) void k_conv2m(
    const unsigned short* __restrict__ h,
    const unsigned short* __restrict__ wt,
    float* __restrict__ p0, float* __restrict__ p1,
    float* __restrict__ p2, float* __restrict__ p3)
{
    __shared__ unsigned short smem[14336];   // 28672 B
    const int t = threadIdx.x;
    const int w = t >> 6, l = t & 63;
    const int mb = blockIdx.x, nb = blockIdx.y, zz = blockIdx.z;
    const int half = zz >> 1, seg = zz & 1;

    const unsigned short* src;
    int nld, sbase;
    unsigned rowbase[8];
    if (w < 2) {
        src = h; nld = 6; sbase = w * 3072;
        #pragma unroll
        for (int ld = 0; ld < 6; ld++) {
            int row = w * 48 + ld * 8 + (l >> 3);      // pixel local 0..95
            int c = l & 7;
            int g = c ^ (row & 7);
            int P = mb * 96 + row;
            int b = P / 36, o = P % 36;
            int oy = o / 6, ox = o % 6;
            rowbase[ld] = (unsigned)((b * 400 + oy * 40 + ox * 2) * 256 + half * 128 + g * 8);
        }
    } else {
        src = wt; nld = 8; sbase = 6144 + (w - 2) * 4096;
        #pragma unroll
        for (int ld = 0; ld < 8; ld++) {
            int oc = (w - 2) * 64 + ld * 8 + (l >> 3); // oc local 0..127
            int c = l & 7;
            int g = c ^ (oc & 7);
            rowbase[ld] = (unsigned)((nb * 128 + oc) * 256 + half * 128 + g * 8);
        }
    }

    const int wm = w & 1, wn = w >> 1;
    const int lane16 = l & 15, q = l >> 4;

    f32x4 acc[3][4] = {};

    const int pos0 = seg ? 41 : 0;
    const int pos1 = seg ? 81 : 41;
    for (int pos = pos0; pos < pos1; ++pos) {
        const int ky = pos / 9, kx = pos - ky * 9;
        const unsigned kbase = (w < 2) ? (unsigned)((ky * 20 + kx) * 256)
                                       : (unsigned)(pos * 65536);
        for (int icc = 0; icc < 2; ++icc) {
            const unsigned kofs = kbase + icc * 64;
            __syncthreads();
            for (int ld = 0; ld < nld; ld++) {
                __builtin_amdgcn_global_load_lds(
                    (const __attribute__((address_space(1))) unsigned int*)(const void*)(src + rowbase[ld] + kofs),
                    (__attribute__((address_space(3))) unsigned int*)(void*)(smem + sbase + ld * 512),
                    16, 0, 0);
            }
            __syncthreads();
            #pragma unroll
            for (int ic2 = 0; ic2 < 2; ic2++) {
                short8 a[3], b[4];
                #pragma unroll
                for (int mt = 0; mt < 3; mt++) {
                    int pixL = wm * 48 + mt * 16 + lane16;
                    int ps = (ic2 * 4 + q) ^ (pixL & 7);
                    a[mt] = *(const short8*)(smem + pixL * 64 + ps * 8);
                }
                #pragma unroll
                for (int nt = 0; nt < 4; nt++) {
                    int ocL = wn * 64 + nt * 16 + lane16;
                    int ps = (ic2 * 4 + q) ^ (ocL & 7);
                    b[nt] = *(const short8*)(smem + 6144 + ocL * 64 + ps * 8);
                }
                #pragma unroll
                for (int mt = 0; mt < 3; mt++)
                    #pragma unroll
                    for (int nt = 0; nt < 4; nt++)
                        acc[mt][nt] = __builtin_amdgcn_mfma_f32_16x16x32_bf16(a[mt], b[nt], acc[mt][nt], 0, 0, 0);
            }
        }
    }

    #pragma unroll
    for (int mt = 0; mt < 3; mt++) {
        int pixG = mb * 96 + wm * 48 + mt * 16 + q * 4;
        int b = pixG / 36, p36 = pixG % 36;
        #pragma unroll
        for (int nt = 0; nt < 4; nt++) {
            int oc = nb * 128 + wn * 64 + nt * 16 + lane16;
            float* pout = (zz == 0) ? p0 : (zz == 1) ? p1 : (zz == 2) ? p2 : p3;
            *(f32x4*)&pout[((size_t)(b * 256 + oc)) * 36 + p36] = acc[mt][nt];
        }
    }
}

// Fused squash1 + dwt2: blocks 0..2047 squash, 2048..2207 dwt2.
__global__ void k_sq1dw(const float* __restrict__ q0, const float* __restrict__ q1,
                        const float* __restrict__ q2, const float* __restrict__ q3,
                        const float* __restrict__ prim_b, float* __restrict__ U,
                        const float* __restrict__ dw, float* __restrict__ dwT2) {
    __shared__ float red[4];
    int blk = blockIdx.x, t = threadIdx.x;
    if (blk < 2048) {
        int b = blk >> 3, cap = blk & 7;
        size_t base = ((size_t)b * 256 + cap * 32) * 36;
        const float* pa = q0 + base;
        const float* pb = q1 + base;
        const float* pc = q2 + base;
        const float* pd = q3 + base;
        float v[5];
        float ss = 0.f;
        #pragma unroll
        for (int j = 0; j < 5; j++) {
            int idx = t + j * 256;
            if (idx < 1152) {
                int ch_l = idx / 36;
                float val = pa[idx] + pb[idx] + pc[idx] + pd[idx] + prim_b[cap * 32 + ch_l];
                v[j] = val; ss += val * val;
            } else v[j] = 0.f;
        }
        for (int off = 32; off; off >>= 1) ss += __shfl_down(ss, off);
        if ((t & 63) == 0) red[t >> 6] = ss;
        __syncthreads();
        float n2 = red[0] + red[1] + red[2] + red[3];
        float f = (n2 / (1.0f + n2)) / (sqrtf(n2) + 1e-10f);
        #pragma unroll
        for (int j = 0; j < 5; j++) {
            int idx = t + j * 256;
            if (idx < 1152) U[(size_t)b * 9216 + idx * 8 + cap] = v[j] * f;
        }
    } else {
        int co = blk - 2048;
        int c = co >> 4, o = co & 15;
        const float* base = dw + c * 128 + o * 8;
        float* out = dwT2 + (size_t)co * 9216;
        for (int idx = t; idx < 9216; idx += 256) {
            int i = idx >> 3, k = idx & 7;
            out[idx] = base[(size_t)i * 1280 + k];
        }
    }
}

__global__ void k_softmax(const float* __restrict__ bij, float* __restrict__ csm) {
    __shared__ float red[4];
    int c = blockIdx.x, t = threadIdx.x;
    float vals[5];
    float mx = -1e30f;
    #pragma unroll
    for (int j = 0; j < 5; j++) {
        int i = t + j * 256;
        vals[j] = (i < 1152) ? bij[i * 10 + c] : -1e30f;
        mx = fmaxf(mx, vals[j]);
    }
    for (int off = 32; off; off >>= 1) mx = fmaxf(mx, __shfl_down(mx, off));
    if ((t & 63) == 0) red[t >> 6] = mx;
    __syncthreads();
    mx = fmaxf(fmaxf(red[0], red[1]), fmaxf(red[2], red[3]));
    __syncthreads();
    float s = 0.f;
    #pragma unroll
    for (int j = 0; j < 5; j++) {
        int i = t + j * 256;
        vals[j] = (i < 1152) ? expf(vals[j] - mx) : 0.f;
        s += vals[j];
    }
    for (int off = 32; off; off >>= 1) s += __shfl_down(s, off);
    if ((t & 63) == 0) red[t >> 6] = s;
    __syncthreads();
    s = red[0] + red[1] + red[2] + red[3];
    float inv = 1.0f / s;
    #pragma unroll
    for (int j = 0; j < 5; j++) {
        int i = t + j * 256;
        if (i < 1152) csm[i * 10 + c] = vals[j] * inv;
    }
}

// s_j partial GEMM. A-panel register cache + b128 swizzled WsT reads.
// grid (8 mb, 32 kc), block 256. part[kc][row][160].
__global__ __launch_bounds__(256) void k_gemm1(const float* __restrict__ U,
                                               const float* __restrict__ dwT2,
                                               const float* __restrict__ csm,
                                               float* __restrict__ part,
                                               int uniform) {
    __shared__ float Us[32 * 36];     // [row][kk 32 +pad]
    __shared__ float WsT[5120];       // [co160][chunk8 swizzled][4]
    __shared__ float cl[360];
    int mb = blockIdx.x, kc = blockIdx.y, t = threadIdx.x;
    int tc = t & 15, tb = t >> 4;
    if (!uniform)
        for (int idx = t; idx < 360; idx += 256) cl[idx] = csm[kc * 360 + idx];
    const float uscale = 1.0f / 1152.0f;
    float acc[2][10] = {};
    for (int ks = 0; ks < 9; ks++) {
        __syncthreads();
        {   // stage Us: 32 rows x 32 kk
            int bb = t >> 3, k4 = t & 7;
            *(float4*)&Us[bb * 36 + k4 * 4] =
                *(const float4*)&U[(size_t)(mb * 32 + bb) * 9216 + kc * 288 + ks * 32 + k4 * 4];
        }
        // stage WsT lane-linear with chunk swizzle; fold c_ij
        #pragma unroll
        for (int pass = 0; pass < 5; pass++) {
            int s = t + pass * 256;
            int co = s >> 3, p = s & 7;
            int kq = p ^ (co & 7);
            int ikl = ks * 32 + kq * 4;
            float4 v = *(const float4*)&dwT2[(size_t)co * 9216 + kc * 288 + ikl];
            float sc = uniform ? uscale : cl[(ikl >> 3) * 10 + (co >> 4)];
            v.x *= sc; v.y *= sc; v.z *= sc; v.w *= sc;
            *(float4*)&WsT[s * 4] = v;
        }
        __syncthreads();
        // A-panel into registers: 2 rows x 32 kk
        float a0[32], a1[32];
        #pragma unroll
        for (int kq = 0; kq < 8; kq++) {
            float4 v0 = *(const float4*)&Us[(tb * 2) * 36 + kq * 4];
            float4 v1 = *(const float4*)&Us[(tb * 2 + 1) * 36 + kq * 4];
            a0[kq * 4 + 0] = v0.x; a0[kq * 4 + 1] = v0.y; a0[kq * 4 + 2] = v0.z; a0[kq * 4 + 3] = v0.w;
            a1[kq * 4 + 0] = v1.x; a1[kq * 4 + 1] = v1.y; a1[kq * 4 + 2] = v1.z; a1[kq * 4 + 3] = v1.w;
        }
        #pragma unroll
        for (int j = 0; j < 10; j++) {
            int co = tc + 16 * j;
            int cx = co & 7, cbase = co * 32;
            #pragma unroll
            for (int kq = 0; kq < 8; kq++) {
                float4 wv = *(const float4*)&WsT[cbase + ((kq ^ cx) << 2)];
                acc[0][j] += a0[kq * 4 + 0] * wv.x; acc[0][j] += a0[kq * 4 + 1] * wv.y;
                acc[0][j] += a0[kq * 4 + 2] * wv.z; acc[0][j] += a0[kq * 4 + 3] * wv.w;
                acc[1][j] += a1[kq * 4 + 0] * wv.x; acc[1][j] += a1[kq * 4 + 1] * wv.y;
                acc[1][j] += a1[kq * 4 + 2] * wv.z; acc[1][j] += a1[kq * 4 + 3] * wv.w;
            }
        }
    }
    #pragma unroll
    for (int r = 0; r < 2; r++)
        #pragma unroll
        for (int j = 0; j < 10; j++)
            part[(size_t)kc * 40960 + (mb * 32 + tb * 2 + r) * 160 + tc + 16 * j] = acc[r][j];
}

__global__ void k_redsq(const float* __restrict__ part, float* __restrict__ out,
                        float* __restrict__ outT, int writeT) {
    __shared__ float sl[160];
    __shared__ float n2s[16];
    int b = blockIdx.x, t = threadIdx.x;
    float s = 0.f;
    if (t < 160) {
        for (int kc = 0; kc < 32; kc++) s += part[(size_t)kc * 40960 + b * 160 + t];
        sl[t] = s;
    }
    __syncthreads();
    if (t < 16) {
        float n2 = 0.f;
        #pragma unroll
        for (int c = 0; c < 10; c++) { float v = sl[c * 16 + t]; n2 += v * v; }
        n2s[t] = n2;
    }
    __syncthreads();
    if (t < 160) {
        float n2 = n2s[t & 15];
        float f = (n2 / (1.0f + n2)) / (sqrtf(n2) + 1e-10f);
        float r = s * f;
        out[(size_t)b * 160 + t] = r;
        if (writeT) outT[(size_t)t * 256 + b] = r;
    }
}

// Fused agreement with in-LDS U-tile transpose. grid 288, block 256.
// first=1: store into bij (replaces memset); else accumulate.
__global__ __launch_bounds__(256) void k_g2uv(const float* __restrict__ U,
                                              const float* __restrict__ outTg,
                                              const float* __restrict__ dw,
                                              float* __restrict__ bij,
                                              int first) {
    __shared__ float UsT[1024];    // [m32][chunk8 swizzled][4]
    __shared__ float OsT[5120];    // [co160][chunk8 swizzled][4]
    __shared__ float dwl[5120];
    __shared__ float sb[320];
    int blk = blockIdx.x, t = threadIdx.x;
    int tc = t & 15, tm = t >> 4;
    for (int idx = t; idx < 5120; idx += 256)
        dwl[idx] = dw[(size_t)blk * 5120 + idx];
    float acc[2][10] = {};
    for (int bs = 0; bs < 256; bs += 32) {
        __syncthreads();
        {   // in-LDS transpose of U[bs..bs+32)[blk*32..+32) into UsT layout
            int r = t >> 3, c4 = t & 7;
            float4 v = *(const float4*)&U[(size_t)(bs + r) * 9216 + blk * 32 + c4 * 4];
            int hi = (r >> 2), lo = (r & 3);
            int m0 = c4 * 4;
            UsT[(m0 + 0) * 32 + ((hi ^ ((m0 + 0) & 7)) << 2) + lo] = v.x;
            UsT[(m0 + 1) * 32 + ((hi ^ ((m0 + 1) & 7)) << 2) + lo] = v.y;
            UsT[(m0 + 2) * 32 + ((hi ^ ((m0 + 2) & 7)) << 2) + lo] = v.z;
            UsT[(m0 + 3) * 32 + ((hi ^ ((m0 + 3) & 7)) << 2) + lo] = v.w;
        }
        #pragma unroll
        for (int pass = 0; pass < 5; pass++) {
            int s = t + pass * 256;
            int co = s >> 3, p = s & 7;
            int kq = p ^ (co & 7);
            *(float4*)&OsT[s * 4] =
                *(const float4*)&outTg[(size_t)co * 256 + bs + kq * 4];
        }
        __syncthreads();
        float a0[32], a1[32];
        int m0 = tm * 2, m1 = tm * 2 + 1;
        #pragma unroll
        for (int kq = 0; kq < 8; kq++) {
            float4 v0 = *(const float4*)&UsT[m0 * 32 + ((kq ^ (m0 & 7)) << 2)];
            float4 v1 = *(const float4*)&UsT[m1 * 32 + ((kq ^ (m1 & 7)) << 2)];
            a0[kq * 4 + 0] = v0.x; a0[kq * 4 + 1] = v0.y; a0[kq * 4 + 2] = v0.z; a0[kq * 4 + 3] = v0.w;
            a1[kq * 4 + 0] = v1.x; a1[kq * 4 + 1] = v1.y; a1[kq * 4 + 2] = v1.z; a1[kq * 4 + 3] = v1.w;
        }
        #pragma unroll
        for (int j = 0; j < 10; j++) {
            int co = tc + 16 * j;
            int cx = co & 7, cbase = co * 32;
            #pragma unroll
            for (int kq = 0; kq < 8; kq++) {
                float4 wv = *(const float4*)&OsT[cbase + ((kq ^ cx) << 2)];
                acc[0][j] += a0[kq * 4 + 0] * wv.x; acc[0][j] += a0[kq * 4 + 1] * wv.y;
                acc[0][j] += a0[kq * 4 + 2] * wv.z; acc[0][j] += a0[kq * 4 + 3] * wv.w;
                acc[1][j] += a1[kq * 4 + 0] * wv.x; acc[1][j] += a1[kq * 4 + 1] * wv.y;
                acc[1][j] += a1[kq * 4 + 2] * wv.z; acc[1][j] += a1[kq * 4 + 3] * wv.w;
            }
        }
    }
    // contract with dw over o (=tc) per (ik_local, c)
    #pragma unroll
    for (int r = 0; r < 2; r++) {
        int ik_l = tm * 2 + r;
        int i_l = ik_l >> 3, k = ik_l & 7;
        #pragma unroll
        for (int j = 0; j < 10; j++) {
            float v = acc[r][j] * dwl[i_l * 1280 + (j * 16 + tc) * 8 + k];
            v += __shfl_down(v, 8, 16);
            v += __shfl_down(v, 4, 16);
            v += __shfl_down(v, 2, 16);
            v += __shfl_down(v, 1, 16);
            if (tc == 0) sb[ik_l * 10 + j] = v;
        }
    }
    __syncthreads();
    if (t < 40) {
        int i_l = t / 10, c = t % 10;
        float s = 0.f;
        #pragma unroll
        for (int kk = 0; kk < 8; kk++) s += sb[(i_l * 8 + kk) * 10 + c];
        size_t o = (size_t)(blk * 4 + i_l) * 10 + c;
        float v = s * (1.0f / 256.0f);
        bij[o] = first ? v : (bij[o] + v);
    }
}

extern "C" void kernel_launch(void* const* d_in, const int* in_sizes, int n_in,
                              void* d_out, int out_size, void* d_ws, size_t ws_size,
                              hipStream_t stream) {
    const float* x      = (const float*)d_in[0];
    const float* conv_w = (const float*)d_in[1];
    const float* conv_b = (const float*)d_in[2];
    const float* prim_w = (const float*)d_in[3];
    const float* prim_b = (const float*)d_in[4];
    const float* dw     = (const float*)d_in[5];

    char* wsb = (char*)d_ws;
    unsigned short* h  = (unsigned short*)(wsb);
    float* dwT2 = (float*)(wsb);               // aliases h (dead after conv2m)
    unsigned short* wt = (unsigned short*)(wsb + 52428800);
    float* pp0  = (float*)(wsb + 63045632);
    float* pp1  = (float*)(wsb + 72482816);
    float* U    = (float*)(wsb + 81920000);
    float* pp3  = (float*)(wsb + 91357184);
    float* part = (float*)(wsb + 97255424);
    float* csm  = (float*)(wsb + 102498304);
    float* bij  = (float*)(wsb + 102544384);
    float* outT = (float*)(wsb + 102590464);
    float* outw = (float*)(wsb + 102754304);
    float* pp2  = (float*)(wsb + 102918144);

    k_pre<<<4096, 256, 0, stream>>>(x, conv_w, conv_b, prim_w, h, wt);
    k_conv2m<<<dim3(96, 2, 4), 256, 0, stream>>>(h, wt, pp0, pp1, pp2, pp3);
    k_sq1dw<<<2208, 256, 0, stream>>>(pp0, pp1, pp2, pp3, prim_b, U, dw, dwT2);

    // iter 0 (uniform c); g2uv stores bij (no memset needed)
    k_gemm1<<<dim3(8, 32), 256, 0, stream>>>(U, dwT2, csm, part, 1);
    k_redsq<<<256, 256, 0, stream>>>(part, outw, outT, 1);
    k_g2uv<<<288, 256, 0, stream>>>(U, outT, dw, bij, 1);
    k_softmax<<<10, 256, 0, stream>>>(bij, csm);
    // iter 1
    k_gemm1<<<dim3(8, 32), 256, 0, stream>>>(U, dwT2, csm, part, 0);
    k_redsq<<<256, 256, 0, stream>>>(part, outw, outT, 1);
    k_g2uv<<<288, 256, 0, stream>>>(U, outT, dw, bij, 0);
    k_softmax<<<10, 256, 0, stream>>>(bij, csm);
    // iter 2
    k_gemm1<<<dim3(8, 32), 256, 0, stream>>>(U, dwT2, csm, part, 0);
    k_redsq<<<256, 256, 0, stream>>>(part, (float*)d_out, outT, 0);
}

// Round 16
// 468.069 us; speedup vs baseline: 1.1659x; 1.1659x over previous
//
#include <hip/hip_runtime.h>
#include <cstdint>
#include <cstddef>

// ---------------------------------------------------------------------------
// CapsNet forward. Round 21: EXACT revert to R19 (measured 473.0us; best
// config also measured 470.3us at R13 — two-run verified optimum).
//  Complete failed-path ledger (all measured on MI355X):
//   - conv2m pipelined variants (R7-R10): 150-153us vs R6-schedule 142us.
//     Conflicts/drains/barrier-count all exonerated; R6 2-barrier schedule
//     with 3 blocks/CU TLP is the local optimum of this structure.
//   - softmax-into-gemm1 (R12): +27us (256x replicated grid reduction).
//   - cooperative grid.sync (R14): WRONG under graph capture (absmax 1.5e-4).
//   - hand-rolled RMW barrier (R15/R17): correct but ~36us/barrier CONSTANT
//     (per-XCD L2 wb/inv at device scope; poll-rate independent) ->
//     kernel relaunch (~8us) is the cheaper grid-sync primitive on CDNA4.
//   - plain-load barrier poll (R16): HANG (per-XCD L2 not cross-coherent;
//     only device-scope RMWs reach the coherence point).
//   - conv1 reg-window rewrite (R18, R20): win[9][10] forced to scratch by
//     compiler SROA policy (VGPR stuck at 68, WRITE_SIZE 120MB) regardless
//     of __launch_bounds__ -> 150us. Path closed.
//  KEPT wins vs session start (508us): k_pre=conv1+makew fusion,
//  k_sq1dw=squash1+dwt2 fusion (dwT2 in dead h region), no bij memset,
//  UT-free g2uv (in-LDS transpose), 19->13 dispatches (~8us/launch gap).
// Workspace (bytes):
//   h    [0, 52428800)           bf16 [b][pix400][ic256]   (dead after conv2m)
//   dwT2 [0, 5898240)            f32  [co160][ik9216]      (aliases h)
//   wt   [52428800, 63045632)    bf16 [k81][oc256][ic256]
//   pp0  [63045632, 72482816)    f32  partial (half0,seg0) [b][oc][36]
//   pp1  [72482816, 81920000)    f32  partial (half0,seg1)
//   U    [81920000, 91357184)    f32  [b][ik]
//   pp3  [91357184, 100794368)   f32  partial (half1,seg1)
//   part [97255424, 102498304)   f32  [kc32][b256][co160]
//   csm  [102498304,102544384)   f32  [i][c]
//   bij  [102544384,102590464)   f32  [i][c]
//   outT [102590464,102754304)   f32  [co160][b256]
//   outw [102754304,102918144)   f32  [b][co160]
//   pp2  [102918144,112355328)   f32  partial (half1,seg0)
// ---------------------------------------------------------------------------

typedef __attribute__((ext_vector_type(8))) short short8;
typedef __attribute__((ext_vector_type(4))) float f32x4;

#define PHALF 2359296

__device__ __forceinline__ unsigned short f2bf_rn(float x) {
    unsigned u = __float_as_uint(x);
    unsigned r = (u + 0x7fffu + ((u >> 16) & 1u)) >> 16;
    return (unsigned short)r;
}

// Fused preprocessing: blocks 0..2047 conv1, blocks 2048..4095 makew.
__global__ void k_pre(const float* __restrict__ x, const float* __restrict__ cw,
                      const float* __restrict__ cb, const float* __restrict__ w2,
                      unsigned short* __restrict__ h, unsigned short* __restrict__ wt) {
    __shared__ float sh[3376];
    int blk = blockIdx.x, t = threadIdx.x;
    if (blk < 2048) {
        float* img = sh;            // 784
        float* wsm = sh + 784;      // 2592
        int b = blk >> 3, ocg = blk & 7;
        for (int idx = t; idx < 784; idx += 256) img[idx] = x[b * 784 + idx];
        for (int idx = t; idx < 2592; idx += 256) wsm[idx] = cw[ocg * 2592 + idx];
        __syncthreads();
        int oc_l = t & 31, g = t >> 5;
        int oc = ocg * 32 + oc_l;
        float bias = cb[oc];
        const float* wp = &wsm[oc_l * 81];
        for (int q = g; q < 100; q += 8) {
            int py = q / 5, qx = (q % 5) * 4;
            float a0 = bias, a1 = bias, a2 = bias, a3 = bias;
            #pragma unroll
            for (int ky = 0; ky < 9; ky++) {
                const float* ir = &img[(py + ky) * 28 + qx];
                float r[12];
                #pragma unroll
                for (int j = 0; j < 12; j++) r[j] = ir[j];
                #pragma unroll
                for (int kx = 0; kx < 9; kx++) {
                    float w = wp[ky * 9 + kx];
                    a0 += r[kx] * w; a1 += r[kx + 1] * w;
                    a2 += r[kx + 2] * w; a3 += r[kx + 3] * w;
                }
            }
            float v[4] = { fmaxf(a0, 0.f), fmaxf(a1, 0.f), fmaxf(a2, 0.f), fmaxf(a3, 0.f) };
            size_t base = ((size_t)b * 400 + py * 20 + qx) * 256 + oc;
            #pragma unroll
            for (int j = 0; j < 4; j++)
                h[base + (size_t)j * 256] = f2bf_rn(v[j]);
        }
    } else {
        int m2 = blk - 2048;
        int oc = m2 >> 3, icg = m2 & 7;
        float* lw2 = sh;            // 2592 = [32 ic][81 k]
        for (int idx = t; idx < 2592; idx += 256) {
            int ic_l = idx / 81, k = idx % 81;
            lw2[idx] = w2[((size_t)oc * 256 + icg * 32 + ic_l) * 81 + k];
        }
        __syncthreads();
        for (int idx = t; idx < 324; idx += 256) {   // 81 k * 4 slots
            int k = idx >> 2, sl = idx & 3;
            unsigned short hi8[8];
            #pragma unroll
            for (int j = 0; j < 8; j++)
                hi8[j] = f2bf_rn(lw2[(sl * 8 + j) * 81 + k]);
            size_t o = ((size_t)(k * 256 + oc)) * 256 + icg * 32 + sl * 8;
            *(uint4*)&wt[o] = *(uint4*)hi8;
        }
    }
}

// Implicit-GEMM bf16 MFMA conv2 — ROUND-6 schedule (best measured).
// grid (96 mb, 2 nb, 4 zz) = 768 blocks (3/CU), block 256 (4 waves).
__global__ __launch_bounds__(256, 4) void k_conv2m(
    const unsigned short* __restrict__ h,
    const unsigned short* __restrict__ wt,
    float* __restrict__ p0, float* __restrict__ p1,
    float* __restrict__ p2, float* __restrict__ p3)
{
    __shared__ unsigned short smem[14336];   // 28672 B
    const int t = threadIdx.x;
    const int w = t >> 6, l = t & 63;
    const int mb = blockIdx.x, nb = blockIdx.y, zz = blockIdx.z;
    const int half = zz >> 1, seg = zz & 1;

    const unsigned short* src;
    int nld, sbase;
    unsigned rowbase[8];
    if (w < 2) {
        src = h; nld = 6; sbase = w * 3072;
        #pragma unroll
        for (int ld = 0; ld < 6; ld++) {
            int row = w * 48 + ld * 8 + (l >> 3);      // pixel local 0..95
            int c = l & 7;
            int g = c ^ (row & 7);
            int P = mb * 96 + row;
            int b = P / 36, o = P % 36;
            int oy = o / 6, ox = o % 6;
            rowbase[ld] = (unsigned)((b * 400 + oy * 40 + ox * 2) * 256 + half * 128 + g * 8);
        }
    } else {
        src = wt; nld = 8; sbase = 6144 + (w - 2) * 4096;
        #pragma unroll
        for (int ld = 0; ld < 8; ld++) {
            int oc = (w - 2) * 64 + ld * 8 + (l >> 3); // oc local 0..127
            int c = l & 7;
            int g = c ^ (oc & 7);
            rowbase[ld] = (unsigned)((nb * 128 + oc) * 256 + half * 128 + g * 8);
        }
    }

    const int wm = w & 1, wn = w >> 1;
    const int lane16 = l & 15, q = l >> 4;

    f32x4 acc[3][4] = {};

    const int pos0 = seg ? 41 : 0;
    const int pos1 = seg ? 81 : 41;
    for (int pos = pos0; pos < pos1; ++pos) {
        const int ky = pos / 9, kx = pos - ky * 9;
        const unsigned kbase = (w < 2) ? (unsigned)((ky * 20 + kx) * 256)
                                       : (unsigned)(pos * 65536);
        for (int icc = 0; icc < 2; ++icc) {
            const unsigned kofs = kbase + icc * 64;
            __syncthreads();
            for (int ld = 0; ld < nld; ld++) {
                __builtin_amdgcn_global_load_lds(
                    (const __attribute__((address_space(1))) unsigned int*)(const void*)(src + rowbase[ld] + kofs),
                    (__attribute__((address_space(3))) unsigned int*)(void*)(smem + sbase + ld * 512),
                    16, 0, 0);
            }
            __syncthreads();
            #pragma unroll
            for (int ic2 = 0; ic2 < 2; ic2++) {
                short8 a[3], b[4];
                #pragma unroll
                for (int mt = 0; mt < 3; mt++) {
                    int pixL = wm * 48 + mt * 16 + lane16;
                    int ps = (ic2 * 4 + q) ^ (pixL & 7);
                    a[mt] = *(const short8*)(smem + pixL * 64 + ps * 8);
                }
                #pragma unroll
                for (int nt = 0; nt < 4; nt++) {
                    int ocL = wn * 64 + nt * 16 + lane16;
                    int ps = (ic2 * 4 + q) ^ (ocL & 7);
                    b[nt] = *(const short8*)(smem + 6144 + ocL * 64 + ps * 8);
                }
                #pragma unroll
                for (int mt = 0; mt < 3; mt++)
                    #pragma unroll
                    for (int nt = 0; nt < 4; nt++)
                        acc[mt][nt] = __builtin_amdgcn_mfma_f32_16x16x32_bf16(a[mt], b[nt], acc[mt][nt], 0, 0, 0);
            }
        }
    }

    #pragma unroll
    for (int mt = 0; mt < 3; mt++) {
        int pixG = mb * 96 + wm * 48 + mt * 16 + q * 4;
        int b = pixG / 36, p36 = pixG % 36;
        #pragma unroll
        for (int nt = 0; nt < 4; nt++) {
            int oc = nb * 128 + wn * 64 + nt * 16 + lane16;
            float* pout = (zz == 0) ? p0 : (zz == 1) ? p1 : (zz == 2) ? p2 : p3;
            *(f32x4*)&pout[((size_t)(b * 256 + oc)) * 36 + p36] = acc[mt][nt];
        }
    }
}

// Fused squash1 + dwt2: blocks 0..2047 squash, 2048..2207 dwt2.
__global__ void k_sq1dw(const float* __restrict__ q0, const float* __restrict__ q1,
                        const float* __restrict__ q2, const float* __restrict__ q3,
                        const float* __restrict__ prim_b, float* __restrict__ U,
                        const float* __restrict__ dw, float* __restrict__ dwT2) {
    __shared__ float red[4];
    int blk = blockIdx.x, t = threadIdx.x;
    if (blk < 2048) {
        int b = blk >> 3, cap = blk & 7;
        size_t base = ((size_t)b * 256 + cap * 32) * 36;
        const float* pa = q0 + base;
        const float* pb = q1 + base;
        const float* pc = q2 + base;
        const float* pd = q3 + base;
        float v[5];
        float ss = 0.f;
        #pragma unroll
        for (int j = 0; j < 5; j++) {
            int idx = t + j * 256;
            if (idx < 1152) {
                int ch_l = idx / 36;
                float val = pa[idx] + pb[idx] + pc[idx] + pd[idx] + prim_b[cap * 32 + ch_l];
                v[j] = val; ss += val * val;
            } else v[j] = 0.f;
        }
        for (int off = 32; off; off >>= 1) ss += __shfl_down(ss, off);
        if ((t & 63) == 0) red[t >> 6] = ss;
        __syncthreads();
        float n2 = red[0] + red[1] + red[2] + red[3];
        float f = (n2 / (1.0f + n2)) / (sqrtf(n2) + 1e-10f);
        #pragma unroll
        for (int j = 0; j < 5; j++) {
            int idx = t + j * 256;
            if (idx < 1152) U[(size_t)b * 9216 + idx * 8 + cap] = v[j] * f;
        }
    } else {
        int co = blk - 2048;
        int c = co >> 4, o = co & 15;
        const float* base = dw + c * 128 + o * 8;
        float* out = dwT2 + (size_t)co * 9216;
        for (int idx = t; idx < 9216; idx += 256) {
            int i = idx >> 3, k = idx & 7;
            out[idx] = base[(size_t)i * 1280 + k];
        }
    }
}

__global__ void k_softmax(const float* __restrict__ bij, float* __restrict__ csm) {
    __shared__ float red[4];
    int c = blockIdx.x, t = threadIdx.x;
    float vals[5];
    float mx = -1e30f;
    #pragma unroll
    for (int j = 0; j < 5; j++) {
        int i = t + j * 256;
        vals[j] = (i < 1152) ? bij[i * 10 + c] : -1e30f;
        mx = fmaxf(mx, vals[j]);
    }
    for (int off = 32; off; off >>= 1) mx = fmaxf(mx, __shfl_down(mx, off));
    if ((t & 63) == 0) red[t >> 6] = mx;
    __syncthreads();
    mx = fmaxf(fmaxf(red[0], red[1]), fmaxf(red[2], red[3]));
    __syncthreads();
    float s = 0.f;
    #pragma unroll
    for (int j = 0; j < 5; j++) {
        int i = t + j * 256;
        vals[j] = (i < 1152) ? expf(vals[j] - mx) : 0.f;
        s += vals[j];
    }
    for (int off = 32; off; off >>= 1) s += __shfl_down(s, off);
    if ((t & 63) == 0) red[t >> 6] = s;
    __syncthreads();
    s = red[0] + red[1] + red[2] + red[3];
    float inv = 1.0f / s;
    #pragma unroll
    for (int j = 0; j < 5; j++) {
        int i = t + j * 256;
        if (i < 1152) csm[i * 10 + c] = vals[j] * inv;
    }
}

// s_j partial GEMM. A-panel register cache + b128 swizzled WsT reads.
// grid (8 mb, 32 kc), block 256. part[kc][row][160].
__global__ __launch_bounds__(256) void k_gemm1(const float* __restrict__ U,
                                               const float* __restrict__ dwT2,
                                               const float* __restrict__ csm,
                                               float* __restrict__ part,
                                               int uniform) {
    __shared__ float Us[32 * 36];     // [row][kk 32 +pad]
    __shared__ float WsT[5120];       // [co160][chunk8 swizzled][4]
    __shared__ float cl[360];
    int mb = blockIdx.x, kc = blockIdx.y, t = threadIdx.x;
    int tc = t & 15, tb = t >> 4;
    if (!uniform)
        for (int idx = t; idx < 360; idx += 256) cl[idx] = csm[kc * 360 + idx];
    const float uscale = 1.0f / 1152.0f;
    float acc[2][10] = {};
    for (int ks = 0; ks < 9; ks++) {
        __syncthreads();
        {   // stage Us: 32 rows x 32 kk
            int bb = t >> 3, k4 = t & 7;
            *(float4*)&Us[bb * 36 + k4 * 4] =
                *(const float4*)&U[(size_t)(mb * 32 + bb) * 9216 + kc * 288 + ks * 32 + k4 * 4];
        }
        // stage WsT lane-linear with chunk swizzle; fold c_ij
        #pragma unroll
        for (int pass = 0; pass < 5; pass++) {
            int s = t + pass * 256;
            int co = s >> 3, p = s & 7;
            int kq = p ^ (co & 7);
            int ikl = ks * 32 + kq * 4;
            float4 v = *(const float4*)&dwT2[(size_t)co * 9216 + kc * 288 + ikl];
            float sc = uniform ? uscale : cl[(ikl >> 3) * 10 + (co >> 4)];
            v.x *= sc; v.y *= sc; v.z *= sc; v.w *= sc;
            *(float4*)&WsT[s * 4] = v;
        }
        __syncthreads();
        // A-panel into registers: 2 rows x 32 kk
        float a0[32], a1[32];
        #pragma unroll
        for (int kq = 0; kq < 8; kq++) {
            float4 v0 = *(const float4*)&Us[(tb * 2) * 36 + kq * 4];
            float4 v1 = *(const float4*)&Us[(tb * 2 + 1) * 36 + kq * 4];
            a0[kq * 4 + 0] = v0.x; a0[kq * 4 + 1] = v0.y; a0[kq * 4 + 2] = v0.z; a0[kq * 4 + 3] = v0.w;
            a1[kq * 4 + 0] = v1.x; a1[kq * 4 + 1] = v1.y; a1[kq * 4 + 2] = v1.z; a1[kq * 4 + 3] = v1.w;
        }
        #pragma unroll
        for (int j = 0; j < 10; j++) {
            int co = tc + 16 * j;
            int cx = co & 7, cbase = co * 32;
            #pragma unroll
            for (int kq = 0; kq < 8; kq++) {
                float4 wv = *(const float4*)&WsT[cbase + ((kq ^ cx) << 2)];
                acc[0][j] += a0[kq * 4 + 0] * wv.x; acc[0][j] += a0[kq * 4 + 1] * wv.y;
                acc[0][j] += a0[kq * 4 + 2] * wv.z; acc[0][j] += a0[kq * 4 + 3] * wv.w;
                acc[1][j] += a1[kq * 4 + 0] * wv.x; acc[1][j] += a1[kq * 4 + 1] * wv.y;
                acc[1][j] += a1[kq * 4 + 2] * wv.z; acc[1][j] += a1[kq * 4 + 3] * wv.w;
            }
        }
    }
    #pragma unroll
    for (int r = 0; r < 2; r++)
        #pragma unroll
        for (int j = 0; j < 10; j++)
            part[(size_t)kc * 40960 + (mb * 32 + tb * 2 + r) * 160 + tc + 16 * j] = acc[r][j];
}

__global__ void k_redsq(const float* __restrict__ part, float* __restrict__ out,
                        float* __restrict__ outT, int writeT) {
    __shared__ float sl[160];
    __shared__ float n2s[16];
    int b = blockIdx.x, t = threadIdx.x;
    float s = 0.f;
    if (t < 160) {
        for (int kc = 0; kc < 32; kc++) s += part[(size_t)kc * 40960 + b * 160 + t];
        sl[t] = s;
    }
    __syncthreads();
    if (t < 16) {
        float n2 = 0.f;
        #pragma unroll
        for (int c = 0; c < 10; c++) { float v = sl[c * 16 + t]; n2 += v * v; }
        n2s[t] = n2;
    }
    __syncthreads();
    if (t < 160) {
        float n2 = n2s[t & 15];
        float f = (n2 / (1.0f + n2)) / (sqrtf(n2) + 1e-10f);
        float r = s * f;
        out[(size_t)b * 160 + t] = r;
        if (writeT) outT[(size_t)t * 256 + b] = r;
    }
}

// Fused agreement with in-LDS U-tile transpose. grid 288, block 256.
// first=1: store into bij (replaces memset); else accumulate.
__global__ __launch_bounds__(256) void k_g2uv(const float* __restrict__ U,
                                              const float* __restrict__ outTg,
                                              const float* __restrict__ dw,
                                              float* __restrict__ bij,
                                              int first) {
    __shared__ float UsT[1024];    // [m32][chunk8 swizzled][4]
    __shared__ float OsT[5120];    // [co160][chunk8 swizzled][4]
    __shared__ float dwl[5120];
    __shared__ float sb[320];
    int blk = blockIdx.x, t = threadIdx.x;
    int tc = t & 15, tm = t >> 4;
    for (int idx = t; idx < 5120; idx += 256)
        dwl[idx] = dw[(size_t)blk * 5120 + idx];
    float acc[2][10] = {};
    for (int bs = 0; bs < 256; bs += 32) {
        __syncthreads();
        {   // in-LDS transpose of U[bs..bs+32)[blk*32..+32) into UsT layout
            int r = t >> 3, c4 = t & 7;
            float4 v = *(const float4*)&U[(size_t)(bs + r) * 9216 + blk * 32 + c4 * 4];
            int hi = (r >> 2), lo = (r & 3);
            int m0 = c4 * 4;
            UsT[(m0 + 0) * 32 + ((hi ^ ((m0 + 0) & 7)) << 2) + lo] = v.x;
            UsT[(m0 + 1) * 32 + ((hi ^ ((m0 + 1) & 7)) << 2) + lo] = v.y;
            UsT[(m0 + 2) * 32 + ((hi ^ ((m0 + 2) & 7)) << 2) + lo] = v.z;
            UsT[(m0 + 3) * 32 + ((hi ^ ((m0 + 3) & 7)) << 2) + lo] = v.w;
        }
        #pragma unroll
        for (int pass = 0; pass < 5; pass++) {
            int s = t + pass * 256;
            int co = s >> 3, p = s & 7;
            int kq = p ^ (co & 7);
            *(float4*)&OsT[s * 4] =
                *(const float4*)&outTg[(size_t)co * 256 + bs + kq * 4];
        }
        __syncthreads();
        float a0[32], a1[32];
        int m0 = tm * 2, m1 = tm * 2 + 1;
        #pragma unroll
        for (int kq = 0; kq < 8; kq++) {
            float4 v0 = *(const float4*)&UsT[m0 * 32 + ((kq ^ (m0 & 7)) << 2)];
            float4 v1 = *(const float4*)&UsT[m1 * 32 + ((kq ^ (m1 & 7)) << 2)];
            a0[kq * 4 + 0] = v0.x; a0[kq * 4 + 1] = v0.y; a0[kq * 4 + 2] = v0.z; a0[kq * 4 + 3] = v0.w;
            a1[kq * 4 + 0] = v1.x; a1[kq * 4 + 1] = v1.y; a1[kq * 4 + 2] = v1.z; a1[kq * 4 + 3] = v1.w;
        }
        #pragma unroll
        for (int j = 0; j < 10; j++) {
            int co = tc + 16 * j;
            int cx = co & 7, cbase = co * 32;
            #pragma unroll
            for (int kq = 0; kq < 8; kq++) {
                float4 wv = *(const float4*)&OsT[cbase + ((kq ^ cx) << 2)];
                acc[0][j] += a0[kq * 4 + 0] * wv.x; acc[0][j] += a0[kq * 4 + 1] * wv.y;
                acc[0][j] += a0[kq * 4 + 2] * wv.z; acc[0][j] += a0[kq * 4 + 3] * wv.w;
                acc[1][j] += a1[kq * 4 + 0] * wv.x; acc[1][j] += a1[kq * 4 + 1] * wv.y;
                acc[1][j] += a1[kq * 4 + 2] * wv.z; acc[1][j] += a1[kq * 4 + 3] * wv.w;
            }
        }
    }
    // contract with dw over o (=tc) per (ik_local, c)
    #pragma unroll
    for (int r = 0; r < 2; r++) {
        int ik_l = tm * 2 + r;
        int i_l = ik_l >> 3, k = ik_l & 7;
        #pragma unroll
        for (int j = 0; j < 10; j++) {
            float v = acc[r][j] * dwl[i_l * 1280 + (j * 16 + tc) * 8 + k];
            v += __shfl_down(v, 8, 16);
            v += __shfl_down(v, 4, 16);
            v += __shfl_down(v, 2, 16);
            v += __shfl_down(v, 1, 16);
            if (tc == 0) sb[ik_l * 10 + j] = v;
        }
    }
    __syncthreads();
    if (t < 40) {
        int i_l = t / 10, c = t % 10;
        float s = 0.f;
        #pragma unroll
        for (int kk = 0; kk < 8; kk++) s += sb[(i_l * 8 + kk) * 10 + c];
        size_t o = (size_t)(blk * 4 + i_l) * 10 + c;
        float v = s * (1.0f / 256.0f);
        bij[o] = first ? v : (bij[o] + v);
    }
}

extern "C" void kernel_launch(void* const* d_in, const int* in_sizes, int n_in,
                              void* d_out, int out_size, void* d_ws, size_t ws_size,
                              hipStream_t stream) {
    const float* x      = (const float*)d_in[0];
    const float* conv_w = (const float*)d_in[1];
    const float* conv_b = (const float*)d_in[2];
    const float* prim_w = (const float*)d_in[3];
    const float* prim_b = (const float*)d_in[4];
    const float* dw     = (const float*)d_in[5];

    char* wsb = (char*)d_ws;
    unsigned short* h  = (unsigned short*)(wsb);
    float* dwT2 = (float*)(wsb);               // aliases h (dead after conv2m)
    unsigned short* wt = (unsigned short*)(wsb + 52428800);
    float* pp0  = (float*)(wsb + 63045632);
    float* pp1  = (float*)(wsb + 72482816);
    float* U    = (float*)(wsb + 81920000);
    float* pp3  = (float*)(wsb + 91357184);
    float* part = (float*)(wsb + 97255424);
    float* csm  = (float*)(wsb + 102498304);
    float* bij  = (float*)(wsb + 102544384);
    float* outT = (float*)(wsb + 102590464);
    float* outw = (float*)(wsb + 102754304);
    float* pp2  = (float*)(wsb + 102918144);

    k_pre<<<4096, 256, 0, stream>>>(x, conv_w, conv_b, prim_w, h, wt);
    k_conv2m<<<dim3(96, 2, 4), 256, 0, stream>>>(h, wt, pp0, pp1, pp2, pp3);
    k_sq1dw<<<2208, 256, 0, stream>>>(pp0, pp1, pp2, pp3, prim_b, U, dw, dwT2);

    // iter 0 (uniform c); g2uv stores bij (no memset needed)
    k_gemm1<<<dim3(8, 32), 256, 0, stream>>>(U, dwT2, csm, part, 1);
    k_redsq<<<256, 256, 0, stream>>>(part, outw, outT, 1);
    k_g2uv<<<288, 256, 0, stream>>>(U, outT, dw, bij, 1);
    k_softmax<<<10, 256, 0, stream>>>(bij, csm);
    // iter 1
    k_gemm1<<<dim3(8, 32), 256, 0, stream>>>(U, dwT2, csm, part, 0);
    k_redsq<<<256, 256, 0, stream>>>(part, outw, outT, 1);
    k_g2uv<<<288, 256, 0, stream>>>(U, outT, dw, bij, 0);
    k_softmax<<<10, 256, 0, stream>>>(bij, csm);
    // iter 2
    k_gemm1<<<dim3(8, 32), 256, 0, stream>>>(U, dwT2, csm, part, 0);
    k_redsq<<<256, 256, 0, stream>>>(part, (float*)d_out, outT, 0);
}